// Round 1
// baseline (1094.684 us; speedup 1.0000x reference)
//
#include <hip/hip_runtime.h>

#define NN 100000
#define NE 3200000
#define NF 512
#define NH 128
#define NC 40

// ---------------- norm prep ----------------

__global__ __launch_bounds__(256) void k_init(float* __restrict__ deg, int* __restrict__ cnt) {
  int i = blockIdx.x * 256 + threadIdx.x;
  if (i < NN) { deg[i] = 1.0f; cnt[i] = 0; }   // self-loop weight 1
}

__global__ __launch_bounds__(256) void k_deg(const int* __restrict__ col, const float* __restrict__ w,
                                             float* __restrict__ deg, int* __restrict__ cnt) {
  int e = blockIdx.x * 256 + threadIdx.x;
  if (e < NE) {
    int c = col[e];
    atomicAdd(&deg[c], w[e]);
    atomicAdd(&cnt[c], 1);
  }
}

__global__ __launch_bounds__(256) void k_rsqrt(float* __restrict__ deg) {
  int i = blockIdx.x * 256 + threadIdx.x;
  if (i < NN) { float d = deg[i]; deg[i] = (d > 0.0f) ? rsqrtf(d) : 0.0f; }
}

// ---------------- exclusive scan of cnt -> rowptr (chunks of 1024) ----------------

__global__ __launch_bounds__(256) void k_scan_sum(const int* __restrict__ cnt, int* __restrict__ bsum) {
  __shared__ int sm[256];
  int t = threadIdx.x;
  int base = blockIdx.x * 1024;
  int s = 0;
#pragma unroll
  for (int j = 0; j < 4; ++j) { int i = base + t + j * 256; if (i < NN) s += cnt[i]; }
  sm[t] = s; __syncthreads();
  for (int off = 128; off > 0; off >>= 1) { if (t < off) sm[t] += sm[t + off]; __syncthreads(); }
  if (t == 0) bsum[blockIdx.x] = sm[0];
}

__global__ __launch_bounds__(128) void k_scan_top(const int* __restrict__ bsum, int* __restrict__ boff, int nb) {
  __shared__ int sm[128];
  int t = threadIdx.x;
  sm[t] = (t < nb) ? bsum[t] : 0;
  __syncthreads();
  for (int off = 1; off < 128; off <<= 1) {
    int add = (t >= off) ? sm[t - off] : 0;
    __syncthreads();
    sm[t] += add;
    __syncthreads();
  }
  if (t < nb) boff[t] = (t == 0) ? 0 : sm[t - 1];
}

__global__ __launch_bounds__(256) void k_scan_final(int* __restrict__ cnt, const int* __restrict__ boff,
                                                    int* __restrict__ rowptr) {
  __shared__ int sm[256];
  int t = threadIdx.x;
  int base = blockIdx.x * 1024 + t * 4;
  int v[4]; int s = 0;
#pragma unroll
  for (int j = 0; j < 4; ++j) {
    int i = base + j;
    int c = (i < NN) ? cnt[i] : 0;
    v[j] = s; s += c;
  }
  sm[t] = s; __syncthreads();
  for (int off = 1; off < 256; off <<= 1) {
    int add = (t >= off) ? sm[t - off] : 0;
    __syncthreads();
    sm[t] += add;
    __syncthreads();
  }
  int texc = (t == 0) ? 0 : sm[t - 1];
  int bo = boff[blockIdx.x];
#pragma unroll
  for (int j = 0; j < 4; ++j) {
    int i = base + j;
    if (i < NN) { rowptr[i] = bo + texc + v[j]; cnt[i] = 0; }  // re-zero cnt for scatter
  }
  if (blockIdx.x == 0 && t == 0) rowptr[NN] = NE;
}

// ---------------- scatter edges into CSR buckets (src, norm packed) ----------------

__global__ __launch_bounds__(256) void k_scatter(const int* __restrict__ row, const int* __restrict__ col,
                                                 const float* __restrict__ w, const float* __restrict__ dinv,
                                                 const int* __restrict__ rowptr, int* __restrict__ cnt,
                                                 int2* __restrict__ pair) {
  int e = blockIdx.x * 256 + threadIdx.x;
  if (e < NE) {
    int r = row[e], c = col[e];
    float nm = dinv[r] * w[e] * dinv[c];
    int pos = rowptr[c] + atomicAdd(&cnt[c], 1);
    pair[pos] = make_int2(r, __float_as_int(nm));
  }
}

// ---------------- GEMM1: hx = x @ W1   (100000x512 @ 512x128, f32) ----------------

__global__ __launch_bounds__(256) void k_gemm1(const float* __restrict__ X, const float* __restrict__ W,
                                               float* __restrict__ HX) {
  __shared__ float As[16][64];   // [k][m]
  __shared__ float Bs[16][NH];   // [k][n]
  int t = threadIdx.x;
  int m0 = blockIdx.x * 64;
  int lr = t >> 2, lk = (t & 3) * 4;      // A-load: row, k-chunk
  int br = t >> 4, bc = (t & 15) * 8;     // B-load
  int tr = t >> 4, tc = t & 15;           // compute: 16x16 thread grid, 4x8 micro-tile
  float acc[4][8];
#pragma unroll
  for (int i = 0; i < 4; ++i)
#pragma unroll
    for (int j = 0; j < 8; ++j) acc[i][j] = 0.0f;
  int arow = m0 + lr;
  for (int k0 = 0; k0 < NF; k0 += 16) {
    float4 av = (arow < NN) ? *(const float4*)(X + (size_t)arow * NF + k0 + lk)
                            : make_float4(0.f, 0.f, 0.f, 0.f);
    float4 b0 = *(const float4*)(W + (size_t)(k0 + br) * NH + bc);
    float4 b1v = *(const float4*)(W + (size_t)(k0 + br) * NH + bc + 4);
    As[lk + 0][lr] = av.x; As[lk + 1][lr] = av.y; As[lk + 2][lr] = av.z; As[lk + 3][lr] = av.w;
    *(float4*)&Bs[br][bc] = b0;
    *(float4*)&Bs[br][bc + 4] = b1v;
    __syncthreads();
#pragma unroll
    for (int kk = 0; kk < 16; ++kk) {
      float4 a = *(const float4*)&As[kk][tr * 4];
      float4 p = *(const float4*)&Bs[kk][tc * 8];
      float4 q = *(const float4*)&Bs[kk][tc * 8 + 4];
      float ar[4] = {a.x, a.y, a.z, a.w};
      float bb[8] = {p.x, p.y, p.z, p.w, q.x, q.y, q.z, q.w};
#pragma unroll
      for (int i = 0; i < 4; ++i)
#pragma unroll
        for (int j = 0; j < 8; ++j) acc[i][j] = fmaf(ar[i], bb[j], acc[i][j]);
    }
    __syncthreads();
  }
#pragma unroll
  for (int i = 0; i < 4; ++i) {
    int rowi = m0 + tr * 4 + i;
    if (rowi < NN) {
      float4 o0 = make_float4(acc[i][0], acc[i][1], acc[i][2], acc[i][3]);
      float4 o1 = make_float4(acc[i][4], acc[i][5], acc[i][6], acc[i][7]);
      *(float4*)(HX + (size_t)rowi * NH + tc * 8) = o0;
      *(float4*)(HX + (size_t)rowi * NH + tc * 8 + 4) = o1;
    }
  }
}

// ---------------- agg1: h = relu(sum_e norm*hx[src] + dinv^2*hx[n] + b1) ----------------

__global__ __launch_bounds__(256) void k_agg1(const int* __restrict__ rowptr, const int2* __restrict__ pair,
                                              const float* __restrict__ hx, const float* __restrict__ dinv,
                                              const float* __restrict__ b1, float* __restrict__ h) {
  int wid = (blockIdx.x * 256 + threadIdx.x) >> 6;  // node = wave id
  int lane = threadIdx.x & 63;
  if (wid >= NN) return;
  int beg = rowptr[wid], end = rowptr[wid + 1];
  const float2* hx2 = (const float2*)hx;
  float ax = 0.f, ay = 0.f;
  int e = beg;
  for (; e + 2 <= end; e += 2) {
    int2 p0 = pair[e];
    int2 p1 = pair[e + 1];
    float2 v0 = hx2[(size_t)p0.x * 64 + lane];
    float2 v1 = hx2[(size_t)p1.x * 64 + lane];
    float n0 = __int_as_float(p0.y), n1 = __int_as_float(p1.y);
    ax = fmaf(n0, v0.x, ax); ay = fmaf(n0, v0.y, ay);
    ax = fmaf(n1, v1.x, ax); ay = fmaf(n1, v1.y, ay);
  }
  if (e < end) {
    int2 p0 = pair[e];
    float2 v0 = hx2[(size_t)p0.x * 64 + lane];
    float n0 = __int_as_float(p0.y);
    ax = fmaf(n0, v0.x, ax); ay = fmaf(n0, v0.y, ay);
  }
  float di = dinv[wid], sl = di * di;
  float2 own = hx2[(size_t)wid * 64 + lane];
  ax = fmaf(sl, own.x, ax); ay = fmaf(sl, own.y, ay);
  float2 bb = ((const float2*)b1)[lane];
  float2 r;
  r.x = fmaxf(ax + bb.x, 0.f);
  r.y = fmaxf(ay + bb.y, 0.f);
  ((float2*)h)[(size_t)wid * 64 + lane] = r;
}

// ---------------- GEMM2: h2 = h @ W2   (100000x128 @ 128x40, f32) ----------------

__global__ __launch_bounds__(256) void k_gemm2(const float* __restrict__ H, const float* __restrict__ W2,
                                               float* __restrict__ H2) {
  __shared__ float Hs[32][132];       // padded, 16B-aligned rows
  __shared__ float Ws[NH * NC];
  int t = threadIdx.x;
  int m0 = blockIdx.x * 32;
  {
    int r = t >> 3, c = (t & 7) * 16;
    int rowi = m0 + r;
#pragma unroll
    for (int j = 0; j < 4; ++j) {
      float4 v = (rowi < NN) ? *(const float4*)(H + (size_t)rowi * NH + c + j * 4)
                             : make_float4(0.f, 0.f, 0.f, 0.f);
      *(float4*)&Hs[r][c + j * 4] = v;
    }
  }
  for (int i = t; i < NH * NC; i += 256) Ws[i] = W2[i];
  __syncthreads();
  int r = t >> 3, c0 = (t & 7) * 5;
  float acc[5] = {0.f, 0.f, 0.f, 0.f, 0.f};
#pragma unroll 4
  for (int k = 0; k < NH; ++k) {
    float hv = Hs[r][k];
#pragma unroll
    for (int j = 0; j < 5; ++j) acc[j] = fmaf(hv, Ws[k * NC + c0 + j], acc[j]);
  }
  int rowi = m0 + r;
  if (rowi < NN) {
#pragma unroll
    for (int j = 0; j < 5; ++j) H2[(size_t)rowi * NC + c0 + j] = acc[j];
  }
}

// ---------------- agg2: out = sum_e norm*h2[src] + dinv^2*h2[n] + b2 ----------------

__global__ __launch_bounds__(256) void k_agg2(const int* __restrict__ rowptr, const int2* __restrict__ pair,
                                              const float* __restrict__ h2, const float* __restrict__ dinv,
                                              const float* __restrict__ b2, float* __restrict__ out) {
  int wid = (blockIdx.x * 256 + threadIdx.x) >> 6;
  int lane = threadIdx.x & 63;
  if (wid >= NN) return;
  int lc = (lane < NC) ? lane : 0;   // lanes >= 40 compute dummy, masked at store
  int beg = rowptr[wid], end = rowptr[wid + 1];
  float acc = 0.f;
  int e = beg;
  for (; e + 2 <= end; e += 2) {
    int2 p0 = pair[e], p1 = pair[e + 1];
    float v0 = h2[(size_t)p0.x * NC + lc];
    float v1 = h2[(size_t)p1.x * NC + lc];
    acc = fmaf(__int_as_float(p0.y), v0, acc);
    acc = fmaf(__int_as_float(p1.y), v1, acc);
  }
  if (e < end) {
    int2 p0 = pair[e];
    acc = fmaf(__int_as_float(p0.y), h2[(size_t)p0.x * NC + lc], acc);
  }
  float di = dinv[wid], sl = di * di;
  acc = fmaf(sl, h2[(size_t)wid * NC + lc], acc);
  if (lane < NC) out[(size_t)wid * NC + lane] = acc + b2[lane];
}

// ---------------- host launch ----------------

extern "C" void kernel_launch(void* const* d_in, const int* in_sizes, int n_in,
                              void* d_out, int out_size, void* d_ws, size_t ws_size,
                              hipStream_t stream) {
  const float* x  = (const float*)d_in[0];
  const int*   ei = (const int*)d_in[1];
  const float* ew = (const float*)d_in[2];
  const float* W1 = (const float*)d_in[3];
  const float* b1 = (const float*)d_in[4];
  const float* W2 = (const float*)d_in[5];
  const float* b2 = (const float*)d_in[6];
  float* out = (float*)d_out;
  const int* row = ei;        // edge_index[0]
  const int* col = ei + NE;   // edge_index[1]

  char* ws = (char*)d_ws;
  size_t o = 0;
  auto alloc = [&](size_t bytes) -> void* {
    void* p = ws + o;
    o += (bytes + 255) & ~(size_t)255;
    return p;
  };
  float* deg    = (float*)alloc((size_t)NN * 4);         // becomes dinv in-place
  int*   cnt    = (int*)alloc((size_t)NN * 4);
  int*   rowptr = (int*)alloc((size_t)(NN + 1) * 4);
  int*   bsum   = (int*)alloc(1024);
  int*   boff   = (int*)alloc(1024);
  int2*  pair   = (int2*)alloc((size_t)NE * 8);
  float* hx     = (float*)alloc((size_t)NN * NH * 4);
  float* h      = (float*)alloc((size_t)NN * NH * 4);
  float* h2     = hx;  // reuse hx region for layer-2 activations (16 MB < 51 MB)

  const int NB = (NN + 1023) / 1024;  // 98

  k_init<<<(NN + 255) / 256, 256, 0, stream>>>(deg, cnt);
  k_deg<<<NE / 256, 256, 0, stream>>>(col, ew, deg, cnt);
  k_rsqrt<<<(NN + 255) / 256, 256, 0, stream>>>(deg);
  k_scan_sum<<<NB, 256, 0, stream>>>(cnt, bsum);
  k_scan_top<<<1, 128, 0, stream>>>(bsum, boff, NB);
  k_scan_final<<<NB, 256, 0, stream>>>(cnt, boff, rowptr);
  k_scatter<<<NE / 256, 256, 0, stream>>>(row, col, ew, deg, rowptr, cnt, pair);
  k_gemm1<<<(NN + 63) / 64, 256, 0, stream>>>(x, W1, hx);
  k_agg1<<<(NN * 64) / 256, 256, 0, stream>>>(rowptr, pair, hx, deg, b1, h);
  k_gemm2<<<(NN + 31) / 32, 256, 0, stream>>>(h, W2, h2);
  k_agg2<<<(NN * 64) / 256, 256, 0, stream>>>(rowptr, pair, h2, deg, b2, out);
}

// Round 2
// 820.210 us; speedup vs baseline: 1.3346x; 1.3346x over previous
//
#include <hip/hip_runtime.h>

#define NN 100000
#define NE 3200000
#define NF 512
#define NH 128
#define NC 40

typedef __attribute__((ext_vector_type(8))) short bfrag;      // 8 bf16 (4 VGPRs)
typedef __attribute__((ext_vector_type(4))) float f32x4;
typedef __attribute__((ext_vector_type(8))) unsigned short u16x8;

static __device__ __forceinline__ unsigned short f2bf(float x) {
  unsigned u = __float_as_uint(x);
  u += 0x7FFF + ((u >> 16) & 1);          // RNE
  return (unsigned short)(u >> 16);
}
static __device__ __forceinline__ float bf2f(unsigned short b) {
  return __uint_as_float(((unsigned)b) << 16);
}

// ---------------- zero packed histogram ----------------

__global__ __launch_bounds__(256) void k_zero(unsigned long long* __restrict__ packed) {
  int i = blockIdx.x * 256 + threadIdx.x;
  if (i < NN) packed[i] = 0ULL;
}

// ---------------- degree histogram: ONE packed 64-bit atomic, rank harvested ----------------

__global__ __launch_bounds__(256) void k_deg(const int* __restrict__ col, const float* __restrict__ w,
                                             unsigned long long* __restrict__ packed,
                                             int* __restrict__ rank) {
  int e = blockIdx.x * 256 + threadIdx.x;
  if (e < NE) {
    int c = col[e];
    unsigned long long v = (1ULL << 42)
        | (unsigned long long)(unsigned)(w[e] * 16777216.0f + 0.5f);
    unsigned long long old = atomicAdd(&packed[c], v);
    rank[e] = (int)(old >> 42);
  }
}

__global__ __launch_bounds__(256) void k_dinv(const unsigned long long* __restrict__ packed,
                                              float* __restrict__ dinv) {
  int i = blockIdx.x * 256 + threadIdx.x;
  if (i < NN) {
    float d = (float)(packed[i] & 0x3FFFFFFFFFFULL) * (1.0f / 16777216.0f) + 1.0f;
    dinv[i] = rsqrtf(d);
  }
}

// ---------------- exclusive scan of counts -> rowptr ----------------

__global__ __launch_bounds__(256) void k_scan_sum(const unsigned long long* __restrict__ packed,
                                                  int* __restrict__ bsum) {
  __shared__ int sm[256];
  int t = threadIdx.x;
  int base = blockIdx.x * 1024;
  int s = 0;
#pragma unroll
  for (int j = 0; j < 4; ++j) { int i = base + t + j * 256; if (i < NN) s += (int)(packed[i] >> 42); }
  sm[t] = s; __syncthreads();
  for (int off = 128; off > 0; off >>= 1) { if (t < off) sm[t] += sm[t + off]; __syncthreads(); }
  if (t == 0) bsum[blockIdx.x] = sm[0];
}

__global__ __launch_bounds__(128) void k_scan_top(const int* __restrict__ bsum, int* __restrict__ boff, int nb) {
  __shared__ int sm[128];
  int t = threadIdx.x;
  sm[t] = (t < nb) ? bsum[t] : 0;
  __syncthreads();
  for (int off = 1; off < 128; off <<= 1) {
    int add = (t >= off) ? sm[t - off] : 0;
    __syncthreads();
    sm[t] += add;
    __syncthreads();
  }
  if (t < nb) boff[t] = (t == 0) ? 0 : sm[t - 1];
}

__global__ __launch_bounds__(256) void k_scan_final(const unsigned long long* __restrict__ packed,
                                                    const int* __restrict__ boff,
                                                    int* __restrict__ rowptr) {
  __shared__ int sm[256];
  int t = threadIdx.x;
  int base = blockIdx.x * 1024 + t * 4;
  int v[4]; int s = 0;
#pragma unroll
  for (int j = 0; j < 4; ++j) {
    int i = base + j;
    int c = (i < NN) ? (int)(packed[i] >> 42) : 0;
    v[j] = s; s += c;
  }
  sm[t] = s; __syncthreads();
  for (int off = 1; off < 256; off <<= 1) {
    int add = (t >= off) ? sm[t - off] : 0;
    __syncthreads();
    sm[t] += add;
    __syncthreads();
  }
  int texc = (t == 0) ? 0 : sm[t - 1];
  int bo = boff[blockIdx.x];
#pragma unroll
  for (int j = 0; j < 4; ++j) {
    int i = base + j;
    if (i < NN) rowptr[i] = bo + texc + v[j];
  }
  if (blockIdx.x == 0 && t == 0) rowptr[NN] = NE;
}

// ---------------- scatter edges into CSR buckets — NO atomics (rank precomputed) ----------------

__global__ __launch_bounds__(256) void k_scatter(const int* __restrict__ row, const int* __restrict__ col,
                                                 const float* __restrict__ w, const int* __restrict__ rank,
                                                 const float* __restrict__ dinv,
                                                 const int* __restrict__ rowptr,
                                                 int2* __restrict__ pair) {
  int e = blockIdx.x * 256 + threadIdx.x;
  if (e < NE) {
    int r = row[e], c = col[e];
    float nm = dinv[r] * w[e] * dinv[c];
    int pos = rowptr[c] + rank[e];
    pair[pos] = make_int2(r, __float_as_int(nm));
  }
}

// ---------------- W1 -> split-bf16 fragment layout [64 kb][128 n][8 j] ----------------

__global__ __launch_bounds__(256) void k_wconv(const float* __restrict__ W1,
                                               unsigned short* __restrict__ Wfh,
                                               unsigned short* __restrict__ Wfl) {
  int i = blockIdx.x * 256 + threadIdx.x;  // 65536 = 512*128
  int k = i >> 7, n = i & 127;
  float w = W1[i];
  unsigned short hi = f2bf(w);
  unsigned short lo = f2bf(w - bf2f(hi));
  int idx = ((k >> 3) * 128 + n) * 8 + (k & 7);
  Wfh[idx] = hi; Wfl[idx] = lo;
}

// ---------------- GEMM1: hx = x @ W1 via bf16 MFMA, 3-term split precision ----------------
// block: 128(M)x128(N), 256 thr = 4 waves (2x2), wave tile 64x64, K-step 32.

__global__ __launch_bounds__(256) void k_gemm1(const float* __restrict__ X,
                                               const unsigned short* __restrict__ Wfh,
                                               const unsigned short* __restrict__ Wfl,
                                               float* __restrict__ HX) {
  __shared__ unsigned short Ah[4096], Al[4096], Bh[4096], Bl[4096];  // each [4 kb][128][8]
  int t = threadIdx.x;
  int lane = t & 63;
  int wid = t >> 6;
  int m0 = blockIdx.x * 128;
  // staging role: row sm, k-half skh (16 f32 each)
  int sm = t & 127;
  int skh = t >> 7;
  const float* xrow = X + (size_t)(m0 + sm) * NF + skh * 16;
  bool mok = (m0 + sm) < NN;
  // compute role
  int wm = wid >> 1, wn = wid & 1;
  int mb = wm * 64, nb = wn * 64;
  int fr = lane & 15, fg = lane >> 4;

  f32x4 acc[4][4];
#pragma unroll
  for (int i = 0; i < 4; ++i)
#pragma unroll
    for (int j = 0; j < 4; ++j) acc[i][j] = (f32x4)0.0f;

  for (int ks = 0; ks < 16; ++ks) {
    // ---- stage B (hi/lo): contiguous 8 KB slabs, raw copy
    {
      const u16x8* sh = (const u16x8*)(Wfh + (size_t)ks * 4096);
      const u16x8* sl = (const u16x8*)(Wfl + (size_t)ks * 4096);
      u16x8 b0 = sh[t], b1 = sh[t + 256];
      u16x8 c0 = sl[t], c1 = sl[t + 256];
      ((u16x8*)Bh)[t] = b0; ((u16x8*)Bh)[t + 256] = b1;
      ((u16x8*)Bl)[t] = c0; ((u16x8*)Bl)[t + 256] = c1;
    }
    // ---- stage A: 16 f32 per thread, convert to bf16 hi + residual lo
    {
      float4 xv[4];
#pragma unroll
      for (int q = 0; q < 4; ++q) {
        xv[q] = mok ? *(const float4*)(xrow + ks * 32 + q * 4)
                    : make_float4(0.f, 0.f, 0.f, 0.f);
      }
#pragma unroll
      for (int q = 0; q < 4; ++q) {
        float f[4] = {xv[q].x, xv[q].y, xv[q].z, xv[q].w};
        unsigned short h[4], l[4];
#pragma unroll
        for (int j = 0; j < 4; ++j) {
          h[j] = f2bf(f[j]);
          l[j] = f2bf(f[j] - bf2f(h[j]));
        }
        int lk = skh * 16 + q * 4;
        int base = (((lk >> 3)) * 128 + sm) * 8 + (lk & 7);
        uint2 hv = make_uint2((unsigned)h[0] | ((unsigned)h[1] << 16),
                              (unsigned)h[2] | ((unsigned)h[3] << 16));
        uint2 lv = make_uint2((unsigned)l[0] | ((unsigned)l[1] << 16),
                              (unsigned)l[2] | ((unsigned)l[3] << 16));
        *(uint2*)&Ah[base] = hv;
        *(uint2*)&Al[base] = lv;
      }
    }
    __syncthreads();
    // ---- fragments
    bfrag ah[4], al[4], bhf[4], blf[4];
#pragma unroll
    for (int mi = 0; mi < 4; ++mi) {
      int idx = (fg * 128 + mb + mi * 16 + fr) * 8;
      ah[mi] = *(bfrag*)&Ah[idx];
      al[mi] = *(bfrag*)&Al[idx];
    }
#pragma unroll
    for (int nt = 0; nt < 4; ++nt) {
      int idx = (fg * 128 + nb + nt * 16 + fr) * 8;
      bhf[nt] = *(bfrag*)&Bh[idx];
      blf[nt] = *(bfrag*)&Bl[idx];
    }
#pragma unroll
    for (int mi = 0; mi < 4; ++mi)
#pragma unroll
      for (int nt = 0; nt < 4; ++nt) {
        acc[mi][nt] = __builtin_amdgcn_mfma_f32_16x16x32_bf16(ah[mi], bhf[nt], acc[mi][nt], 0, 0, 0);
        acc[mi][nt] = __builtin_amdgcn_mfma_f32_16x16x32_bf16(al[mi], bhf[nt], acc[mi][nt], 0, 0, 0);
        acc[mi][nt] = __builtin_amdgcn_mfma_f32_16x16x32_bf16(ah[mi], blf[nt], acc[mi][nt], 0, 0, 0);
      }
    __syncthreads();
  }
  // ---- store: D[r][c], r = fg*4+q, c = fr
#pragma unroll
  for (int mi = 0; mi < 4; ++mi) {
    int rb = m0 + mb + mi * 16 + fg * 4;
#pragma unroll
    for (int nt = 0; nt < 4; ++nt) {
      int c = nb + nt * 16 + fr;
#pragma unroll
      for (int q = 0; q < 4; ++q) {
        int r = rb + q;
        if (r < NN) HX[(size_t)r * NH + c] = acc[mi][nt][q];
      }
    }
  }
}

// ---------------- agg1: h = relu(sum_e norm*hx[src] + dinv^2*hx[n] + b1) ----------------

__global__ __launch_bounds__(256) void k_agg1(const int* __restrict__ rowptr, const int2* __restrict__ pair,
                                              const float* __restrict__ hx, const float* __restrict__ dinv,
                                              const float* __restrict__ b1, float* __restrict__ h) {
  int wid = (blockIdx.x * 256 + threadIdx.x) >> 6;
  int lane = threadIdx.x & 63;
  if (wid >= NN) return;
  int beg = rowptr[wid], end = rowptr[wid + 1];
  const float2* hx2 = (const float2*)hx;
  float ax = 0.f, ay = 0.f;
  int e = beg;
  for (; e + 2 <= end; e += 2) {
    int2 p0 = pair[e];
    int2 p1 = pair[e + 1];
    float2 v0 = hx2[(size_t)p0.x * 64 + lane];
    float2 v1 = hx2[(size_t)p1.x * 64 + lane];
    float n0 = __int_as_float(p0.y), n1 = __int_as_float(p1.y);
    ax = fmaf(n0, v0.x, ax); ay = fmaf(n0, v0.y, ay);
    ax = fmaf(n1, v1.x, ax); ay = fmaf(n1, v1.y, ay);
  }
  if (e < end) {
    int2 p0 = pair[e];
    float2 v0 = hx2[(size_t)p0.x * 64 + lane];
    float n0 = __int_as_float(p0.y);
    ax = fmaf(n0, v0.x, ax); ay = fmaf(n0, v0.y, ay);
  }
  float di = dinv[wid], sl = di * di;
  float2 own = hx2[(size_t)wid * 64 + lane];
  ax = fmaf(sl, own.x, ax); ay = fmaf(sl, own.y, ay);
  float2 bb = ((const float2*)b1)[lane];
  float2 r;
  r.x = fmaxf(ax + bb.x, 0.f);
  r.y = fmaxf(ay + bb.y, 0.f);
  ((float2*)h)[(size_t)wid * 64 + lane] = r;
}

// ---------------- GEMM2: h2 = h @ W2 ----------------

__global__ __launch_bounds__(256) void k_gemm2(const float* __restrict__ H, const float* __restrict__ W2,
                                               float* __restrict__ H2) {
  __shared__ float Hs[32][132];
  __shared__ float Ws[NH * NC];
  int t = threadIdx.x;
  int m0 = blockIdx.x * 32;
  {
    int r = t >> 3, c = (t & 7) * 16;
    int rowi = m0 + r;
#pragma unroll
    for (int j = 0; j < 4; ++j) {
      float4 v = (rowi < NN) ? *(const float4*)(H + (size_t)rowi * NH + c + j * 4)
                             : make_float4(0.f, 0.f, 0.f, 0.f);
      *(float4*)&Hs[r][c + j * 4] = v;
    }
  }
  for (int i = t; i < NH * NC; i += 256) Ws[i] = W2[i];
  __syncthreads();
  int r = t >> 3, c0 = (t & 7) * 5;
  float acc[5] = {0.f, 0.f, 0.f, 0.f, 0.f};
#pragma unroll 4
  for (int k = 0; k < NH; ++k) {
    float hv = Hs[r][k];
#pragma unroll
    for (int j = 0; j < 5; ++j) acc[j] = fmaf(hv, Ws[k * NC + c0 + j], acc[j]);
  }
  int rowi = m0 + r;
  if (rowi < NN) {
#pragma unroll
    for (int j = 0; j < 5; ++j) H2[(size_t)rowi * NC + c0 + j] = acc[j];
  }
}

// ---------------- agg2 ----------------

__global__ __launch_bounds__(256) void k_agg2(const int* __restrict__ rowptr, const int2* __restrict__ pair,
                                              const float* __restrict__ h2, const float* __restrict__ dinv,
                                              const float* __restrict__ b2, float* __restrict__ out) {
  int wid = (blockIdx.x * 256 + threadIdx.x) >> 6;
  int lane = threadIdx.x & 63;
  if (wid >= NN) return;
  int lc = (lane < NC) ? lane : 0;
  int beg = rowptr[wid], end = rowptr[wid + 1];
  float acc = 0.f;
  int e = beg;
  for (; e + 2 <= end; e += 2) {
    int2 p0 = pair[e], p1 = pair[e + 1];
    float v0 = h2[(size_t)p0.x * NC + lc];
    float v1 = h2[(size_t)p1.x * NC + lc];
    acc = fmaf(__int_as_float(p0.y), v0, acc);
    acc = fmaf(__int_as_float(p1.y), v1, acc);
  }
  if (e < end) {
    int2 p0 = pair[e];
    acc = fmaf(__int_as_float(p0.y), h2[(size_t)p0.x * NC + lc], acc);
  }
  float di = dinv[wid], sl = di * di;
  acc = fmaf(sl, h2[(size_t)wid * NC + lc], acc);
  if (lane < NC) out[(size_t)wid * NC + lane] = acc + b2[lane];
}

// ---------------- host launch ----------------

extern "C" void kernel_launch(void* const* d_in, const int* in_sizes, int n_in,
                              void* d_out, int out_size, void* d_ws, size_t ws_size,
                              hipStream_t stream) {
  const float* x  = (const float*)d_in[0];
  const int*   ei = (const int*)d_in[1];
  const float* ew = (const float*)d_in[2];
  const float* W1 = (const float*)d_in[3];
  const float* b1 = (const float*)d_in[4];
  const float* W2 = (const float*)d_in[5];
  const float* b2 = (const float*)d_in[6];
  float* out = (float*)d_out;
  const int* row = ei;
  const int* col = ei + NE;

  char* ws = (char*)d_ws;
  size_t o = 0;
  auto alloc = [&](size_t bytes) -> void* {
    void* p = ws + o;
    o += (bytes + 255) & ~(size_t)255;
    return p;
  };
  float* dinv   = (float*)alloc((size_t)NN * 4);
  int*   rowptr = (int*)alloc((size_t)(NN + 1) * 4);
  int*   bsum   = (int*)alloc(1024);
  int*   boff   = (int*)alloc(1024);
  int2*  pair   = (int2*)alloc((size_t)NE * 8);
  unsigned short* Wfh = (unsigned short*)alloc((size_t)NF * NH * 2);
  unsigned short* Wfl = (unsigned short*)alloc((size_t)NF * NH * 2);
  float* hx     = (float*)alloc((size_t)NN * NH * 4);
  float* h      = (float*)alloc((size_t)NN * NH * 4);
  // aliases (lifetimes disjoint in stream order):
  int* rank = (int*)hx;                           // dead before k_gemm1 writes hx
  unsigned long long* packed = (unsigned long long*)h;  // dead before k_agg1 writes h
  float* h2 = hx;                                 // hx dead after k_agg1

  const int NB = (NN + 1023) / 1024;  // 98

  k_zero<<<(NN + 255) / 256, 256, 0, stream>>>(packed);
  k_wconv<<<(NF * NH) / 256, 256, 0, stream>>>(W1, Wfh, Wfl);
  k_deg<<<NE / 256, 256, 0, stream>>>(col, ew, packed, rank);
  k_scan_sum<<<NB, 256, 0, stream>>>(packed, bsum);
  k_scan_top<<<1, 128, 0, stream>>>(bsum, boff, NB);
  k_scan_final<<<NB, 256, 0, stream>>>(packed, boff, rowptr);
  k_dinv<<<(NN + 255) / 256, 256, 0, stream>>>(packed, dinv);
  k_scatter<<<NE / 256, 256, 0, stream>>>(row, col, ew, rank, dinv, rowptr, pair);
  k_gemm1<<<(NN + 127) / 128, 256, 0, stream>>>(x, Wfh, Wfl, hx);
  k_agg1<<<(NN * 64) / 256, 256, 0, stream>>>(rowptr, pair, hx, dinv, b1, h);
  k_gemm2<<<(NN + 31) / 32, 256, 0, stream>>>(h, W2, h2);
  k_agg2<<<(NN * 64) / 256, 256, 0, stream>>>(rowptr, pair, h2, dinv, b2, out);
}

// Round 3
// 627.383 us; speedup vs baseline: 1.7448x; 1.3074x over previous
//
#include <hip/hip_runtime.h>

#define NN 100000
#define NE 3200000
#define NF 512
#define NH 128
#define NC 40

typedef __attribute__((ext_vector_type(8))) short bfrag;      // 8 bf16 (4 VGPRs)
typedef __attribute__((ext_vector_type(4))) float f32x4;
typedef __attribute__((ext_vector_type(8))) unsigned short u16x8;

static __device__ __forceinline__ unsigned short f2bf(float x) {
  unsigned u = __float_as_uint(x);
  u += 0x7FFF + ((u >> 16) & 1);          // RNE
  return (unsigned short)(u >> 16);
}
static __device__ __forceinline__ float bf2f(unsigned short b) {
  return __uint_as_float(((unsigned)b) << 16);
}

// ---------------- zero packed histogram ----------------

__global__ __launch_bounds__(256) void k_zero(unsigned long long* __restrict__ packed) {
  int i = blockIdx.x * 256 + threadIdx.x;
  if (i < NN) packed[i] = 0ULL;
}

// ---------------- degree histogram: ONE packed 64-bit atomic, rank harvested ----------------

__global__ __launch_bounds__(256) void k_deg(const int* __restrict__ col, const float* __restrict__ w,
                                             unsigned long long* __restrict__ packed,
                                             int* __restrict__ rank) {
  int e = blockIdx.x * 256 + threadIdx.x;
  if (e < NE) {
    int c = col[e];
    unsigned long long v = (1ULL << 42)
        | (unsigned long long)(unsigned)(w[e] * 16777216.0f + 0.5f);
    unsigned long long old = atomicAdd(&packed[c], v);
    rank[e] = (int)(old >> 42);
  }
}

// ---------------- exclusive scan of counts -> rowptr (+ dinv fused) ----------------

__global__ __launch_bounds__(256) void k_scan_sum(const unsigned long long* __restrict__ packed,
                                                  int* __restrict__ bsum) {
  __shared__ int sm[256];
  int t = threadIdx.x;
  int base = blockIdx.x * 1024;
  int s = 0;
#pragma unroll
  for (int j = 0; j < 4; ++j) { int i = base + t + j * 256; if (i < NN) s += (int)(packed[i] >> 42); }
  sm[t] = s; __syncthreads();
  for (int off = 128; off > 0; off >>= 1) { if (t < off) sm[t] += sm[t + off]; __syncthreads(); }
  if (t == 0) bsum[blockIdx.x] = sm[0];
}

__global__ __launch_bounds__(128) void k_scan_top(const int* __restrict__ bsum, int* __restrict__ boff, int nb) {
  __shared__ int sm[128];
  int t = threadIdx.x;
  sm[t] = (t < nb) ? bsum[t] : 0;
  __syncthreads();
  for (int off = 1; off < 128; off <<= 1) {
    int add = (t >= off) ? sm[t - off] : 0;
    __syncthreads();
    sm[t] += add;
    __syncthreads();
  }
  if (t < nb) boff[t] = (t == 0) ? 0 : sm[t - 1];
}

__global__ __launch_bounds__(256) void k_scan_final(const unsigned long long* __restrict__ packed,
                                                    const int* __restrict__ boff,
                                                    int* __restrict__ rowptr,
                                                    float* __restrict__ dinv) {
  __shared__ int sm[256];
  int t = threadIdx.x;
  int base = blockIdx.x * 1024 + t * 4;
  int v[4]; int s = 0;
#pragma unroll
  for (int j = 0; j < 4; ++j) {
    int i = base + j;
    int c = (i < NN) ? (int)(packed[i] >> 42) : 0;
    v[j] = s; s += c;
  }
  sm[t] = s; __syncthreads();
  for (int off = 1; off < 256; off <<= 1) {
    int add = (t >= off) ? sm[t - off] : 0;
    __syncthreads();
    sm[t] += add;
    __syncthreads();
  }
  int texc = (t == 0) ? 0 : sm[t - 1];
  int bo = boff[blockIdx.x];
#pragma unroll
  for (int j = 0; j < 4; ++j) {
    int i = base + j;
    if (i < NN) {
      rowptr[i] = bo + texc + v[j];
      float d = (float)(packed[i] & 0x3FFFFFFFFFFULL) * (1.0f / 16777216.0f) + 1.0f;
      dinv[i] = rsqrtf(d);
    }
  }
  if (blockIdx.x == 0 && t == 0) rowptr[NN] = NE;
}

// ---------------- scatter edges into CSR buckets — NO atomics (rank precomputed) ----------------

__global__ __launch_bounds__(256) void k_scatter(const int* __restrict__ row, const int* __restrict__ col,
                                                 const float* __restrict__ w, const int* __restrict__ rank,
                                                 const float* __restrict__ dinv,
                                                 const int* __restrict__ rowptr,
                                                 int2* __restrict__ pair) {
  int e = blockIdx.x * 256 + threadIdx.x;
  if (e < NE) {
    int r = row[e], c = col[e];
    float nm = dinv[r] * w[e] * dinv[c];
    int pos = rowptr[c] + rank[e];
    pair[pos] = make_int2(r, __float_as_int(nm));
  }
}

// ---------------- W1 -> split-bf16 fragment layout [64 kb][128 n][8 j] ----------------

__global__ __launch_bounds__(256) void k_wconv(const float* __restrict__ W1,
                                               unsigned short* __restrict__ Wfh,
                                               unsigned short* __restrict__ Wfl) {
  int i = blockIdx.x * 256 + threadIdx.x;  // 65536 = 512*128
  int k = i >> 7, n = i & 127;
  float w = W1[i];
  unsigned short hi = f2bf(w);
  unsigned short lo = f2bf(w - bf2f(hi));
  int idx = ((k >> 3) * 128 + n) * 8 + (k & 7);
  Wfh[idx] = hi; Wfl[idx] = lo;
}

// ---------------- GEMM1: hx = x @ W1 via bf16 MFMA, 3-term split; OUTPUT bf16 ----------------

__global__ __launch_bounds__(256) void k_gemm1(const float* __restrict__ X,
                                               const unsigned short* __restrict__ Wfh,
                                               const unsigned short* __restrict__ Wfl,
                                               unsigned short* __restrict__ HXb) {
  __shared__ unsigned short Ah[4096], Al[4096], Bh[4096], Bl[4096];  // each [4 kb][128][8]
  int t = threadIdx.x;
  int lane = t & 63;
  int wid = t >> 6;
  int m0 = blockIdx.x * 128;
  int sm = t & 127;
  int skh = t >> 7;
  const float* xrow = X + (size_t)(m0 + sm) * NF + skh * 16;
  bool mok = (m0 + sm) < NN;
  int wm = wid >> 1, wn = wid & 1;
  int mb = wm * 64, nb = wn * 64;
  int fr = lane & 15, fg = lane >> 4;

  f32x4 acc[4][4];
#pragma unroll
  for (int i = 0; i < 4; ++i)
#pragma unroll
    for (int j = 0; j < 4; ++j) acc[i][j] = (f32x4)0.0f;

  for (int ks = 0; ks < 16; ++ks) {
    {
      const u16x8* sh = (const u16x8*)(Wfh + (size_t)ks * 4096);
      const u16x8* sl = (const u16x8*)(Wfl + (size_t)ks * 4096);
      u16x8 b0 = sh[t], b1 = sh[t + 256];
      u16x8 c0 = sl[t], c1 = sl[t + 256];
      ((u16x8*)Bh)[t] = b0; ((u16x8*)Bh)[t + 256] = b1;
      ((u16x8*)Bl)[t] = c0; ((u16x8*)Bl)[t + 256] = c1;
    }
    {
      float4 xv[4];
#pragma unroll
      for (int q = 0; q < 4; ++q) {
        xv[q] = mok ? *(const float4*)(xrow + ks * 32 + q * 4)
                    : make_float4(0.f, 0.f, 0.f, 0.f);
      }
#pragma unroll
      for (int q = 0; q < 4; ++q) {
        float f[4] = {xv[q].x, xv[q].y, xv[q].z, xv[q].w};
        unsigned short h[4], l[4];
#pragma unroll
        for (int j = 0; j < 4; ++j) {
          h[j] = f2bf(f[j]);
          l[j] = f2bf(f[j] - bf2f(h[j]));
        }
        int lk = skh * 16 + q * 4;
        int base = (((lk >> 3)) * 128 + sm) * 8 + (lk & 7);
        uint2 hv = make_uint2((unsigned)h[0] | ((unsigned)h[1] << 16),
                              (unsigned)h[2] | ((unsigned)h[3] << 16));
        uint2 lv = make_uint2((unsigned)l[0] | ((unsigned)l[1] << 16),
                              (unsigned)l[2] | ((unsigned)l[3] << 16));
        *(uint2*)&Ah[base] = hv;
        *(uint2*)&Al[base] = lv;
      }
    }
    __syncthreads();
    bfrag ah[4], al[4], bhf[4], blf[4];
#pragma unroll
    for (int mi = 0; mi < 4; ++mi) {
      int idx = (fg * 128 + mb + mi * 16 + fr) * 8;
      ah[mi] = *(bfrag*)&Ah[idx];
      al[mi] = *(bfrag*)&Al[idx];
    }
#pragma unroll
    for (int nt = 0; nt < 4; ++nt) {
      int idx = (fg * 128 + nb + nt * 16 + fr) * 8;
      bhf[nt] = *(bfrag*)&Bh[idx];
      blf[nt] = *(bfrag*)&Bl[idx];
    }
#pragma unroll
    for (int mi = 0; mi < 4; ++mi)
#pragma unroll
      for (int nt = 0; nt < 4; ++nt) {
        acc[mi][nt] = __builtin_amdgcn_mfma_f32_16x16x32_bf16(ah[mi], bhf[nt], acc[mi][nt], 0, 0, 0);
        acc[mi][nt] = __builtin_amdgcn_mfma_f32_16x16x32_bf16(al[mi], bhf[nt], acc[mi][nt], 0, 0, 0);
        acc[mi][nt] = __builtin_amdgcn_mfma_f32_16x16x32_bf16(ah[mi], blf[nt], acc[mi][nt], 0, 0, 0);
      }
    __syncthreads();
  }
#pragma unroll
  for (int mi = 0; mi < 4; ++mi) {
    int rb = m0 + mb + mi * 16 + fg * 4;
#pragma unroll
    for (int nt = 0; nt < 4; ++nt) {
      int c = nb + nt * 16 + fr;
#pragma unroll
      for (int q = 0; q < 4; ++q) {
        int r = rb + q;
        if (r < NN) HXb[(size_t)r * NH + c] = f2bf(acc[mi][nt][q]);
      }
    }
  }
}

// ---------------- agg1: h = relu(sum_e norm*hx[src] + dinv^2*hx[n] + b1)  [bf16 in/out] ----------------

__global__ __launch_bounds__(256) void k_agg1(const int* __restrict__ rowptr, const int2* __restrict__ pair,
                                              const unsigned* __restrict__ hxb, const float* __restrict__ dinv,
                                              const float* __restrict__ b1, unsigned* __restrict__ hb) {
  int wid = (blockIdx.x * 256 + threadIdx.x) >> 6;
  int lane = threadIdx.x & 63;
  if (wid >= NN) return;
  int beg = rowptr[wid], end = rowptr[wid + 1];
  float ax = 0.f, ay = 0.f;
  int e = beg;
  for (; e + 4 <= end; e += 4) {
    int2 p0 = pair[e], p1 = pair[e + 1], p2 = pair[e + 2], p3 = pair[e + 3];
    unsigned v0 = hxb[(size_t)p0.x * 64 + lane];
    unsigned v1 = hxb[(size_t)p1.x * 64 + lane];
    unsigned v2 = hxb[(size_t)p2.x * 64 + lane];
    unsigned v3 = hxb[(size_t)p3.x * 64 + lane];
    float n0 = __int_as_float(p0.y), n1 = __int_as_float(p1.y);
    float n2 = __int_as_float(p2.y), n3 = __int_as_float(p3.y);
    ax = fmaf(n0, __uint_as_float(v0 << 16), ax); ay = fmaf(n0, __uint_as_float(v0 & 0xFFFF0000u), ay);
    ax = fmaf(n1, __uint_as_float(v1 << 16), ax); ay = fmaf(n1, __uint_as_float(v1 & 0xFFFF0000u), ay);
    ax = fmaf(n2, __uint_as_float(v2 << 16), ax); ay = fmaf(n2, __uint_as_float(v2 & 0xFFFF0000u), ay);
    ax = fmaf(n3, __uint_as_float(v3 << 16), ax); ay = fmaf(n3, __uint_as_float(v3 & 0xFFFF0000u), ay);
  }
  for (; e < end; ++e) {
    int2 p0 = pair[e];
    unsigned v0 = hxb[(size_t)p0.x * 64 + lane];
    float n0 = __int_as_float(p0.y);
    ax = fmaf(n0, __uint_as_float(v0 << 16), ax); ay = fmaf(n0, __uint_as_float(v0 & 0xFFFF0000u), ay);
  }
  float di = dinv[wid], sl = di * di;
  unsigned own = hxb[(size_t)wid * 64 + lane];
  ax = fmaf(sl, __uint_as_float(own << 16), ax);
  ay = fmaf(sl, __uint_as_float(own & 0xFFFF0000u), ay);
  float2 bb = ((const float2*)b1)[lane];
  float rx = fmaxf(ax + bb.x, 0.f);
  float ry = fmaxf(ay + bb.y, 0.f);
  hb[(size_t)wid * 64 + lane] = (unsigned)f2bf(rx) | ((unsigned)f2bf(ry) << 16);
}

// ---------------- GEMM2: h2 = h @ W2   [h bf16 in, h2 bf16-padded64 out] ----------------

__global__ __launch_bounds__(256) void k_gemm2(const unsigned* __restrict__ hb, const float* __restrict__ W2,
                                               unsigned short* __restrict__ H2b) {
  __shared__ float Hs[32][132];
  __shared__ float Ws[NH * NC];
  int t = threadIdx.x;
  int m0 = blockIdx.x * 32;
  {
    int r = t >> 3, cb = (t & 7) * 8;   // 8 uints = 16 feats per thread
    int rowi = m0 + r;
    if (rowi < NN) {
      uint4 a = *(const uint4*)(hb + (size_t)rowi * 64 + cb);
      uint4 b = *(const uint4*)(hb + (size_t)rowi * 64 + cb + 4);
      unsigned u[8] = {a.x, a.y, a.z, a.w, b.x, b.y, b.z, b.w};
#pragma unroll
      for (int j = 0; j < 8; ++j) {
        Hs[r][cb * 2 + j * 2]     = __uint_as_float(u[j] << 16);
        Hs[r][cb * 2 + j * 2 + 1] = __uint_as_float(u[j] & 0xFFFF0000u);
      }
    } else {
#pragma unroll
      for (int j = 0; j < 16; ++j) Hs[r][cb * 2 + j] = 0.f;
    }
  }
  for (int i = t; i < NH * NC; i += 256) Ws[i] = W2[i];
  __syncthreads();
  int r = t >> 3, c0 = (t & 7) * 5;
  float acc[5] = {0.f, 0.f, 0.f, 0.f, 0.f};
#pragma unroll 4
  for (int k = 0; k < NH; ++k) {
    float hv = Hs[r][k];
#pragma unroll
    for (int j = 0; j < 5; ++j) acc[j] = fmaf(hv, Ws[k * NC + c0 + j], acc[j]);
  }
  int rowi = m0 + r;
  if (rowi < NN) {
#pragma unroll
    for (int j = 0; j < 5; ++j) H2b[(size_t)rowi * 64 + c0 + j] = f2bf(acc[j]);
    int pr = t & 7;
    if (pr < 3) {
#pragma unroll
      for (int j = 0; j < 8; ++j) H2b[(size_t)rowi * 64 + 40 + pr * 8 + j] = 0;
    }
  }
}

// ---------------- agg2: out = sum_e norm*h2[src] + dinv^2*h2[n] + b2  [bf16-padded64 in] ----------------

__global__ __launch_bounds__(256) void k_agg2(const int* __restrict__ rowptr, const int2* __restrict__ pair,
                                              const unsigned short* __restrict__ h2b,
                                              const float* __restrict__ dinv,
                                              const float* __restrict__ b2, float* __restrict__ out) {
  int wid = (blockIdx.x * 256 + threadIdx.x) >> 6;
  int lane = threadIdx.x & 63;
  if (wid >= NN) return;
  int beg = rowptr[wid], end = rowptr[wid + 1];
  float acc = 0.f;
  int e = beg;
  for (; e + 4 <= end; e += 4) {
    int2 p0 = pair[e], p1 = pair[e + 1], p2 = pair[e + 2], p3 = pair[e + 3];
    unsigned short v0 = h2b[(size_t)p0.x * 64 + lane];
    unsigned short v1 = h2b[(size_t)p1.x * 64 + lane];
    unsigned short v2 = h2b[(size_t)p2.x * 64 + lane];
    unsigned short v3 = h2b[(size_t)p3.x * 64 + lane];
    acc = fmaf(__int_as_float(p0.y), bf2f(v0), acc);
    acc = fmaf(__int_as_float(p1.y), bf2f(v1), acc);
    acc = fmaf(__int_as_float(p2.y), bf2f(v2), acc);
    acc = fmaf(__int_as_float(p3.y), bf2f(v3), acc);
  }
  for (; e < end; ++e) {
    int2 p0 = pair[e];
    acc = fmaf(__int_as_float(p0.y), bf2f(h2b[(size_t)p0.x * 64 + lane]), acc);
  }
  float di = dinv[wid], sl = di * di;
  acc = fmaf(sl, bf2f(h2b[(size_t)wid * 64 + lane]), acc);
  if (lane < NC) out[(size_t)wid * NC + lane] = acc + b2[lane];
}

// ---------------- host launch ----------------

extern "C" void kernel_launch(void* const* d_in, const int* in_sizes, int n_in,
                              void* d_out, int out_size, void* d_ws, size_t ws_size,
                              hipStream_t stream) {
  const float* x  = (const float*)d_in[0];
  const int*   ei = (const int*)d_in[1];
  const float* ew = (const float*)d_in[2];
  const float* W1 = (const float*)d_in[3];
  const float* b1 = (const float*)d_in[4];
  const float* W2 = (const float*)d_in[5];
  const float* b2 = (const float*)d_in[6];
  float* out = (float*)d_out;
  const int* row = ei;
  const int* col = ei + NE;

  char* ws = (char*)d_ws;
  size_t o = 0;
  auto alloc = [&](size_t bytes) -> void* {
    void* p = ws + o;
    o += (bytes + 255) & ~(size_t)255;
    return p;
  };
  float* dinv   = (float*)alloc((size_t)NN * 4);
  int*   rowptr = (int*)alloc((size_t)(NN + 1) * 4);
  int*   bsum   = (int*)alloc(1024);
  int*   boff   = (int*)alloc(1024);
  int2*  pair   = (int2*)alloc((size_t)NE * 8);
  unsigned short* Wfh = (unsigned short*)alloc((size_t)NF * NH * 2);
  unsigned short* Wfl = (unsigned short*)alloc((size_t)NF * NH * 2);
  unsigned short* hxb = (unsigned short*)alloc((size_t)NN * NH * 2);   // bf16 hx
  unsigned*       hb  = (unsigned*)alloc((size_t)NN * NH * 2);         // bf16 h (as packed uints)
  unsigned long long* packed = (unsigned long long*)alloc((size_t)NN * 8);
  int* rank = (int*)alloc((size_t)NE * 4);
  unsigned short* h2b = (unsigned short*)hxb;   // hx dead after k_agg1; 100000*64*2 B < hx size

  const int NB = (NN + 1023) / 1024;  // 98

  k_zero<<<(NN + 255) / 256, 256, 0, stream>>>(packed);
  k_wconv<<<(NF * NH) / 256, 256, 0, stream>>>(W1, Wfh, Wfl);
  k_deg<<<NE / 256, 256, 0, stream>>>(col, ew, packed, rank);
  k_scan_sum<<<NB, 256, 0, stream>>>(packed, bsum);
  k_scan_top<<<1, 128, 0, stream>>>(bsum, boff, NB);
  k_scan_final<<<NB, 256, 0, stream>>>(packed, boff, rowptr, dinv);
  k_scatter<<<NE / 256, 256, 0, stream>>>(row, col, ew, rank, dinv, rowptr, pair);
  k_gemm1<<<(NN + 127) / 128, 256, 0, stream>>>(x, Wfh, Wfl, hxb);
  k_agg1<<<(NN * 64) / 256, 256, 0, stream>>>(rowptr, pair, (const unsigned*)hxb, dinv, b1, hb);
  k_gemm2<<<(NN + 31) / 32, 256, 0, stream>>>(hb, W2, h2b);
  k_agg2<<<(NN * 64) / 256, 256, 0, stream>>>(rowptr, pair, h2b, dinv, b2, out);
}

// Round 4
// 475.764 us; speedup vs baseline: 2.3009x; 1.3187x over previous
//
#include <hip/hip_runtime.h>

#define NN 100000
#define NE 3200000
#define NF 512
#define NH 128
#define NC 40
#define NBIN 196      // ceil(NN/512)
#define BINW 512
#define CAP  20480    // per-bin capacity (mean 16384, +32 sigma)
#define EPB  4096     // edges per binA block

typedef __attribute__((ext_vector_type(8))) short bfrag;
typedef __attribute__((ext_vector_type(4))) float f32x4;
typedef __attribute__((ext_vector_type(8))) unsigned short u16x8;

static __device__ __forceinline__ unsigned short f2bf(float x) {
  unsigned u = __float_as_uint(x);
  u += 0x7FFF + ((u >> 16) & 1);          // RNE
  return (unsigned short)(u >> 16);
}
static __device__ __forceinline__ float bf2f(unsigned short b) {
  return __uint_as_float(((unsigned)b) << 16);
}

// ---------------- zero bin fill counters ----------------

__global__ __launch_bounds__(256) void k_zerobins(int* __restrict__ binfill) {
  if (threadIdx.x < NBIN) binfill[threadIdx.x] = 0;
}

// ---------------- Pass A: bin edges by col>>9, LDS histogram + block-level reservation ----------------

__global__ __launch_bounds__(256) void k_binA(const int* __restrict__ row, const int* __restrict__ col,
                                              const float* __restrict__ w,
                                              int* __restrict__ binfill, int2* __restrict__ binned) {
  __shared__ int hist[NBIN];
  __shared__ int base[NBIN];
  int t = threadIdx.x;
  int eb = blockIdx.x * EPB;
  for (int i = t; i < NBIN; i += 256) hist[i] = 0;
  __syncthreads();
  int rk[16], bn[16], sr[16]; float wv[16];
#pragma unroll
  for (int j = 0; j < 16; ++j) {
    int e = eb + t + j * 256;
    if (e < NE) {
      int c = col[e];
      bn[j] = c >> 9;
      sr[j] = row[e] | ((c & 511) << 17);
      wv[j] = w[e];
      rk[j] = atomicAdd(&hist[bn[j]], 1);
    } else bn[j] = -1;
  }
  __syncthreads();
  if (t < NBIN) { int hv = hist[t]; base[t] = hv ? atomicAdd(&binfill[t], hv) : 0; }
  __syncthreads();
#pragma unroll
  for (int j = 0; j < 16; ++j) {
    if (bn[j] >= 0) {
      int pos = base[bn[j]] + rk[j];
      if (pos < CAP) binned[(size_t)bn[j] * CAP + pos] = make_int2(sr[j], __float_as_int(wv[j]));
    }
  }
}

// ---------------- scan bin counts -> binptr; rowptr[NN]=NE ----------------

__global__ __launch_bounds__(256) void k_binscan(const int* __restrict__ binfill,
                                                 int* __restrict__ binptr, int* __restrict__ rowptr) {
  __shared__ int sm[256];
  int t = threadIdx.x;
  sm[t] = (t < NBIN) ? binfill[t] : 0;
  __syncthreads();
  for (int off = 1; off < 256; off <<= 1) {
    int a = (t >= off) ? sm[t - off] : 0;
    __syncthreads();
    sm[t] += a;
    __syncthreads();
  }
  if (t <= NBIN) binptr[t] = (t == 0) ? 0 : sm[t - 1];
  if (t == 0) rowptr[NN] = NE;
}

// ---------------- Pass B: per-bin CSR build via LDS atomics (no global atomics) ----------------

__global__ __launch_bounds__(256) void k_binB(const int* __restrict__ binfill, const int* __restrict__ binptr,
                                              const int2* __restrict__ binned, int2* __restrict__ pair,
                                              int* __restrict__ rowptr, float* __restrict__ dinv) {
  __shared__ unsigned long long pk[BINW];     // count<<42 | fixed-point weight sum
  __shared__ unsigned short lrank[CAP];
  __shared__ int lptr[BINW];
  __shared__ int sm[256];
  int t = threadIdx.x;
  int bin = blockIdx.x;
  int cnt = binfill[bin];
  int bb = binptr[bin];
  pk[t] = 0ULL; pk[t + 256] = 0ULL;
  __syncthreads();
  const int2* src = binned + (size_t)bin * CAP;
  for (int i = t; i < cnt; i += 256) {
    int2 r = src[i];
    int lc = (unsigned)r.x >> 17;
    unsigned long long fw = (unsigned long long)(unsigned)(__int_as_float(r.y) * 16777216.0f + 0.5f);
    unsigned long long old = atomicAdd(&pk[lc], (1ULL << 42) | fw);
    lrank[i] = (unsigned short)(old >> 42);
  }
  __syncthreads();
  int c0 = (int)(pk[2 * t] >> 42), c1 = (int)(pk[2 * t + 1] >> 42);
  sm[t] = c0 + c1;
  __syncthreads();
  for (int off = 1; off < 256; off <<= 1) {
    int a = (t >= off) ? sm[t - off] : 0;
    __syncthreads();
    sm[t] += a;
    __syncthreads();
  }
  int excl = (t == 0) ? 0 : sm[t - 1];
  lptr[2 * t] = excl;
  lptr[2 * t + 1] = excl + c0;
  int n0 = bin * BINW + 2 * t;
  if (n0 < NN) {
    rowptr[n0] = bb + excl;
    float d = (float)(pk[2 * t] & 0x3FFFFFFFFFFULL) * (1.0f / 16777216.0f) + 1.0f;
    dinv[n0] = rsqrtf(d);
  }
  if (n0 + 1 < NN) {
    rowptr[n0 + 1] = bb + excl + c0;
    float d = (float)(pk[2 * t + 1] & 0x3FFFFFFFFFFULL) * (1.0f / 16777216.0f) + 1.0f;
    dinv[n0 + 1] = rsqrtf(d);
  }
  __syncthreads();
  for (int i = t; i < cnt; i += 256) {
    int2 r = src[i];
    int lc = (unsigned)r.x >> 17;
    int pos = bb + lptr[lc] + (int)lrank[i];
    pair[pos] = make_int2(r.x & 0x1FFFF, r.y);
  }
}

// ---------------- Pass C: fold dinv[src] into edge weight ----------------

__global__ __launch_bounds__(256) void k_normC(int2* __restrict__ pair, const float* __restrict__ dinv) {
  int e = blockIdx.x * 256 + threadIdx.x;
  if (e < NE) {
    int2 p = pair[e];
    pair[e].y = __float_as_int(__int_as_float(p.y) * dinv[p.x]);
  }
}

// ---------------- W1 -> split-bf16 fragment layout [64 kb][128 n][8 j] ----------------

__global__ __launch_bounds__(256) void k_wconv(const float* __restrict__ W1,
                                               unsigned short* __restrict__ Wfh,
                                               unsigned short* __restrict__ Wfl) {
  int i = blockIdx.x * 256 + threadIdx.x;
  int k = i >> 7, n = i & 127;
  float w = W1[i];
  unsigned short hi = f2bf(w);
  unsigned short lo = f2bf(w - bf2f(hi));
  int idx = ((k >> 3) * 128 + n) * 8 + (k & 7);
  Wfh[idx] = hi; Wfl[idx] = lo;
}

// ---------------- GEMM1: hx = x @ W1 via bf16 MFMA, 3-term split; OUTPUT bf16 ----------------

__global__ __launch_bounds__(256) void k_gemm1(const float* __restrict__ X,
                                               const unsigned short* __restrict__ Wfh,
                                               const unsigned short* __restrict__ Wfl,
                                               unsigned short* __restrict__ HXb) {
  __shared__ unsigned short Ah[4096], Al[4096], Bh[4096], Bl[4096];
  int t = threadIdx.x;
  int lane = t & 63;
  int wid = t >> 6;
  int m0 = blockIdx.x * 128;
  int sm = t & 127;
  int skh = t >> 7;
  const float* xrow = X + (size_t)(m0 + sm) * NF + skh * 16;
  bool mok = (m0 + sm) < NN;
  int wm = wid >> 1, wn = wid & 1;
  int mb = wm * 64, nb = wn * 64;
  int fr = lane & 15, fg = lane >> 4;

  f32x4 acc[4][4];
#pragma unroll
  for (int i = 0; i < 4; ++i)
#pragma unroll
    for (int j = 0; j < 4; ++j) acc[i][j] = (f32x4)0.0f;

  for (int ks = 0; ks < 16; ++ks) {
    {
      const u16x8* sh = (const u16x8*)(Wfh + (size_t)ks * 4096);
      const u16x8* sl = (const u16x8*)(Wfl + (size_t)ks * 4096);
      u16x8 b0 = sh[t], b1 = sh[t + 256];
      u16x8 c0 = sl[t], c1 = sl[t + 256];
      ((u16x8*)Bh)[t] = b0; ((u16x8*)Bh)[t + 256] = b1;
      ((u16x8*)Bl)[t] = c0; ((u16x8*)Bl)[t + 256] = c1;
    }
    {
      float4 xv[4];
#pragma unroll
      for (int q = 0; q < 4; ++q) {
        xv[q] = mok ? *(const float4*)(xrow + ks * 32 + q * 4)
                    : make_float4(0.f, 0.f, 0.f, 0.f);
      }
#pragma unroll
      for (int q = 0; q < 4; ++q) {
        float f[4] = {xv[q].x, xv[q].y, xv[q].z, xv[q].w};
        unsigned short h[4], l[4];
#pragma unroll
        for (int j = 0; j < 4; ++j) {
          h[j] = f2bf(f[j]);
          l[j] = f2bf(f[j] - bf2f(h[j]));
        }
        int lk = skh * 16 + q * 4;
        int base = (((lk >> 3)) * 128 + sm) * 8 + (lk & 7);
        uint2 hv = make_uint2((unsigned)h[0] | ((unsigned)h[1] << 16),
                              (unsigned)h[2] | ((unsigned)h[3] << 16));
        uint2 lv = make_uint2((unsigned)l[0] | ((unsigned)l[1] << 16),
                              (unsigned)l[2] | ((unsigned)l[3] << 16));
        *(uint2*)&Ah[base] = hv;
        *(uint2*)&Al[base] = lv;
      }
    }
    __syncthreads();
    bfrag ah[4], al[4], bhf[4], blf[4];
#pragma unroll
    for (int mi = 0; mi < 4; ++mi) {
      int idx = (fg * 128 + mb + mi * 16 + fr) * 8;
      ah[mi] = *(bfrag*)&Ah[idx];
      al[mi] = *(bfrag*)&Al[idx];
    }
#pragma unroll
    for (int nt = 0; nt < 4; ++nt) {
      int idx = (fg * 128 + nb + nt * 16 + fr) * 8;
      bhf[nt] = *(bfrag*)&Bh[idx];
      blf[nt] = *(bfrag*)&Bl[idx];
    }
#pragma unroll
    for (int mi = 0; mi < 4; ++mi)
#pragma unroll
      for (int nt = 0; nt < 4; ++nt) {
        acc[mi][nt] = __builtin_amdgcn_mfma_f32_16x16x32_bf16(ah[mi], bhf[nt], acc[mi][nt], 0, 0, 0);
        acc[mi][nt] = __builtin_amdgcn_mfma_f32_16x16x32_bf16(al[mi], bhf[nt], acc[mi][nt], 0, 0, 0);
        acc[mi][nt] = __builtin_amdgcn_mfma_f32_16x16x32_bf16(ah[mi], blf[nt], acc[mi][nt], 0, 0, 0);
      }
    __syncthreads();
  }
#pragma unroll
  for (int mi = 0; mi < 4; ++mi) {
    int rb = m0 + mb + mi * 16 + fg * 4;
#pragma unroll
    for (int nt = 0; nt < 4; ++nt) {
      int c = nb + nt * 16 + fr;
#pragma unroll
      for (int q = 0; q < 4; ++q) {
        int r = rb + q;
        if (r < NN) HXb[(size_t)r * NH + c] = f2bf(acc[mi][nt][q]);
      }
    }
  }
}

// ---------------- agg1: h = relu(dinv_c*acc + dinv_c^2*own + b1)  [bf16 in/out] ----------------

__global__ __launch_bounds__(256) void k_agg1(const int* __restrict__ rowptr, const int2* __restrict__ pair,
                                              const unsigned* __restrict__ hxb, const float* __restrict__ dinv,
                                              const float* __restrict__ b1, unsigned* __restrict__ hb) {
  int wid = (blockIdx.x * 256 + threadIdx.x) >> 6;
  int lane = threadIdx.x & 63;
  if (wid >= NN) return;
  int beg = rowptr[wid], end = rowptr[wid + 1];
  float ax = 0.f, ay = 0.f;
  int e = beg;
  for (; e + 4 <= end; e += 4) {
    int2 p0 = pair[e], p1 = pair[e + 1], p2 = pair[e + 2], p3 = pair[e + 3];
    unsigned v0 = hxb[(size_t)p0.x * 64 + lane];
    unsigned v1 = hxb[(size_t)p1.x * 64 + lane];
    unsigned v2 = hxb[(size_t)p2.x * 64 + lane];
    unsigned v3 = hxb[(size_t)p3.x * 64 + lane];
    float n0 = __int_as_float(p0.y), n1 = __int_as_float(p1.y);
    float n2 = __int_as_float(p2.y), n3 = __int_as_float(p3.y);
    ax = fmaf(n0, __uint_as_float(v0 << 16), ax); ay = fmaf(n0, __uint_as_float(v0 & 0xFFFF0000u), ay);
    ax = fmaf(n1, __uint_as_float(v1 << 16), ax); ay = fmaf(n1, __uint_as_float(v1 & 0xFFFF0000u), ay);
    ax = fmaf(n2, __uint_as_float(v2 << 16), ax); ay = fmaf(n2, __uint_as_float(v2 & 0xFFFF0000u), ay);
    ax = fmaf(n3, __uint_as_float(v3 << 16), ax); ay = fmaf(n3, __uint_as_float(v3 & 0xFFFF0000u), ay);
  }
  for (; e < end; ++e) {
    int2 p0 = pair[e];
    unsigned v0 = hxb[(size_t)p0.x * 64 + lane];
    float n0 = __int_as_float(p0.y);
    ax = fmaf(n0, __uint_as_float(v0 << 16), ax); ay = fmaf(n0, __uint_as_float(v0 & 0xFFFF0000u), ay);
  }
  float di = dinv[wid], sl = di * di;
  unsigned own = hxb[(size_t)wid * 64 + lane];
  float2 bb = ((const float2*)b1)[lane];
  float rx = fmaxf(fmaf(di, ax, fmaf(sl, __uint_as_float(own << 16), bb.x)), 0.f);
  float ry = fmaxf(fmaf(di, ay, fmaf(sl, __uint_as_float(own & 0xFFFF0000u), bb.y)), 0.f);
  hb[(size_t)wid * 64 + lane] = (unsigned)f2bf(rx) | ((unsigned)f2bf(ry) << 16);
}

// ---------------- GEMM2: h2 = h @ W2   [h bf16 in, h2 bf16-padded64 out] ----------------

__global__ __launch_bounds__(256) void k_gemm2(const unsigned* __restrict__ hb, const float* __restrict__ W2,
                                               unsigned short* __restrict__ H2b) {
  __shared__ float Hs[32][132];
  __shared__ float Ws[NH * NC];
  int t = threadIdx.x;
  int m0 = blockIdx.x * 32;
  {
    int r = t >> 3, cb = (t & 7) * 8;
    int rowi = m0 + r;
    if (rowi < NN) {
      uint4 a = *(const uint4*)(hb + (size_t)rowi * 64 + cb);
      uint4 b = *(const uint4*)(hb + (size_t)rowi * 64 + cb + 4);
      unsigned u[8] = {a.x, a.y, a.z, a.w, b.x, b.y, b.z, b.w};
#pragma unroll
      for (int j = 0; j < 8; ++j) {
        Hs[r][cb * 2 + j * 2]     = __uint_as_float(u[j] << 16);
        Hs[r][cb * 2 + j * 2 + 1] = __uint_as_float(u[j] & 0xFFFF0000u);
      }
    } else {
#pragma unroll
      for (int j = 0; j < 16; ++j) Hs[r][cb * 2 + j] = 0.f;
    }
  }
  for (int i = t; i < NH * NC; i += 256) Ws[i] = W2[i];
  __syncthreads();
  int r = t >> 3, c0 = (t & 7) * 5;
  float acc[5] = {0.f, 0.f, 0.f, 0.f, 0.f};
#pragma unroll 4
  for (int k = 0; k < NH; ++k) {
    float hv = Hs[r][k];
#pragma unroll
    for (int j = 0; j < 5; ++j) acc[j] = fmaf(hv, Ws[k * NC + c0 + j], acc[j]);
  }
  int rowi = m0 + r;
  if (rowi < NN) {
#pragma unroll
    for (int j = 0; j < 5; ++j) H2b[(size_t)rowi * 64 + c0 + j] = f2bf(acc[j]);
    int pr = t & 7;
    if (pr < 3) {
#pragma unroll
      for (int j = 0; j < 8; ++j) H2b[(size_t)rowi * 64 + 40 + pr * 8 + j] = 0;
    }
  }
}

// ---------------- agg2: out = dinv_c*acc + dinv_c^2*own + b2  [bf16-padded64 in] ----------------

__global__ __launch_bounds__(256) void k_agg2(const int* __restrict__ rowptr, const int2* __restrict__ pair,
                                              const unsigned short* __restrict__ h2b,
                                              const float* __restrict__ dinv,
                                              const float* __restrict__ b2, float* __restrict__ out) {
  int wid = (blockIdx.x * 256 + threadIdx.x) >> 6;
  int lane = threadIdx.x & 63;
  if (wid >= NN) return;
  int beg = rowptr[wid], end = rowptr[wid + 1];
  float acc = 0.f;
  int e = beg;
  for (; e + 4 <= end; e += 4) {
    int2 p0 = pair[e], p1 = pair[e + 1], p2 = pair[e + 2], p3 = pair[e + 3];
    unsigned short v0 = h2b[(size_t)p0.x * 64 + lane];
    unsigned short v1 = h2b[(size_t)p1.x * 64 + lane];
    unsigned short v2 = h2b[(size_t)p2.x * 64 + lane];
    unsigned short v3 = h2b[(size_t)p3.x * 64 + lane];
    acc = fmaf(__int_as_float(p0.y), bf2f(v0), acc);
    acc = fmaf(__int_as_float(p1.y), bf2f(v1), acc);
    acc = fmaf(__int_as_float(p2.y), bf2f(v2), acc);
    acc = fmaf(__int_as_float(p3.y), bf2f(v3), acc);
  }
  for (; e < end; ++e) {
    int2 p0 = pair[e];
    acc = fmaf(__int_as_float(p0.y), bf2f(h2b[(size_t)p0.x * 64 + lane]), acc);
  }
  float di = dinv[wid], sl = di * di;
  acc = fmaf(di, acc, sl * bf2f(h2b[(size_t)wid * 64 + lane]));
  if (lane < NC) out[(size_t)wid * NC + lane] = acc + b2[lane];
}

// ---------------- host launch ----------------

extern "C" void kernel_launch(void* const* d_in, const int* in_sizes, int n_in,
                              void* d_out, int out_size, void* d_ws, size_t ws_size,
                              hipStream_t stream) {
  const float* x  = (const float*)d_in[0];
  const int*   ei = (const int*)d_in[1];
  const float* ew = (const float*)d_in[2];
  const float* W1 = (const float*)d_in[3];
  const float* b1 = (const float*)d_in[4];
  const float* W2 = (const float*)d_in[5];
  const float* b2 = (const float*)d_in[6];
  float* out = (float*)d_out;
  const int* row = ei;
  const int* col = ei + NE;

  char* ws = (char*)d_ws;
  size_t o = 0;
  auto alloc = [&](size_t bytes) -> void* {
    void* p = ws + o;
    o += (bytes + 255) & ~(size_t)255;
    return p;
  };
  float* dinv    = (float*)alloc((size_t)NN * 4);
  int*   rowptr  = (int*)alloc((size_t)(NN + 1) * 4);
  int*   binfill = (int*)alloc(1024);
  int*   binptr  = (int*)alloc(1024);
  int2*  pair    = (int2*)alloc((size_t)NE * 8);
  unsigned short* Wfh = (unsigned short*)alloc((size_t)NF * NH * 2);
  unsigned short* Wfl = (unsigned short*)alloc((size_t)NF * NH * 2);
  unsigned short* hxb = (unsigned short*)alloc((size_t)NN * NH * 2);
  unsigned*       hb  = (unsigned*)alloc((size_t)NN * NH * 2);
  int2*  binned  = (int2*)alloc((size_t)NBIN * CAP * 8);
  unsigned short* h2b = (unsigned short*)hxb;   // hxb dead after k_agg1

  k_zerobins<<<1, 256, 0, stream>>>(binfill);
  k_wconv<<<(NF * NH) / 256, 256, 0, stream>>>(W1, Wfh, Wfl);
  k_binA<<<(NE + EPB - 1) / EPB, 256, 0, stream>>>(row, col, ew, binfill, binned);
  k_binscan<<<1, 256, 0, stream>>>(binfill, binptr, rowptr);
  k_binB<<<NBIN, 256, 0, stream>>>(binfill, binptr, binned, pair, rowptr, dinv);
  k_normC<<<NE / 256, 256, 0, stream>>>(pair, dinv);
  k_gemm1<<<(NN + 127) / 128, 256, 0, stream>>>(x, Wfh, Wfl, hxb);
  k_agg1<<<(NN * 64) / 256, 256, 0, stream>>>(rowptr, pair, (const unsigned*)hxb, dinv, b1, hb);
  k_gemm2<<<(NN + 31) / 32, 256, 0, stream>>>(hb, W2, h2b);
  k_agg2<<<(NN * 64) / 256, 256, 0, stream>>>(rowptr, pair, h2b, dinv, b2, out);
}